// Round 1
// baseline (151.455 us; speedup 1.0000x reference)
//
#include <hip/hip_runtime.h>

// QLSTM: T=64, B=256, D=512, NQ=6.
// Closed form for _qlayer: with C_w = cos(x_w + theta_w):
//   z0 = C1*C2*C3*C4*C5, z1 = C0*C1, z2 = C0*C1*C2, z3 = C0..C3, z4 = C0..C4, z5 = C0..C5
// Kernel 1: pre[m][g*6+w] = sum_k X[m][k]*Wg[k][w] + b_g[w] + theta_g[w]   (m = t*256+b)
// Kernel 2: sequential scan, a = pre + h@Wh, gates, LSTM update.

__device__ __forceinline__ float fast_rcp(float x) { return __builtin_amdgcn_rcpf(x); }

__global__ __launch_bounds__(256) void gemm_pre(
    const float* __restrict__ X,
    const float* __restrict__ Wf, const float* __restrict__ bf,
    const float* __restrict__ Wi, const float* __restrict__ bi,
    const float* __restrict__ Wu, const float* __restrict__ bu,
    const float* __restrict__ Wo, const float* __restrict__ bo,
    const float* __restrict__ thf, const float* __restrict__ thi,
    const float* __restrict__ thu, const float* __restrict__ tho,
    float* __restrict__ pre)
{
    // Buf: As tile (64 rows x 68 stride = 4352 floats) overlaid with
    // reduction buffer (4 ksub * 64 rows * 24 = 6144 floats).
    __shared__ float Buf[6144];
    __shared__ float Bs[24];

    const int tid = threadIdx.x;
    if (tid < 24) {
        int g = tid / 6, w = tid % 6;
        const float* bb = (g==0)?bf:(g==1)?bi:(g==2)?bu:bo;
        const float* tt = (g==0)?thf:(g==1)?thi:(g==2)?thu:tho;
        Bs[tid] = bb[w] + tt[w];
    }

    const int r    = tid & 63;          // row within block (lane)
    const int ksub = tid >> 6;          // wave id 0..3 -> K quarter
    const int kuni = __builtin_amdgcn_readfirstlane(ksub << 4); // wave-uniform
    const int rowbase = blockIdx.x * 64;

    float acc[24];
    #pragma unroll
    for (int j = 0; j < 24; ++j) acc[j] = 0.f;

    for (int kb = 0; kb < 512; kb += 64) {
        __syncthreads();
        // stage As[64][64] (stride 68): 1024 float4, 4 per thread; 256B
        // contiguous per 16 lanes -> coalesced.
        #pragma unroll
        for (int i = 0; i < 4; ++i) {
            int f  = tid + i*256;
            int rr = f >> 4, k4 = f & 15;
            const float4 v = *(const float4*)(X + (rowbase + rr)*512 + kb + k4*4);
            *(float4*)(&Buf[rr*68 + k4*4]) = v;
        }
        __syncthreads();
        // this wave's 16 k-values of the chunk; W addresses are wave-uniform
        // (kuni via readfirstlane) -> scalar loads, FMAs read W from SGPRs.
        #pragma unroll
        for (int kk4 = 0; kk4 < 4; ++kk4) {
            float4 a4 = *(const float4*)(&Buf[r*68 + kuni + kk4*4]);
            float av[4] = {a4.x, a4.y, a4.z, a4.w};
            #pragma unroll
            for (int q = 0; q < 4; ++q) {
                const int k = kb + kuni + kk4*4 + q;
                const float a = av[q];
                #pragma unroll
                for (int gg = 0; gg < 4; ++gg) {
                    const float* Wp = (gg==0)?Wf:(gg==1)?Wi:(gg==2)?Wu:Wo;
                    const float2* pw = (const float2*)(Wp + k*6);
                    float2 w0 = pw[0], w1 = pw[1], w2 = pw[2];
                    acc[gg*6+0] = fmaf(a, w0.x, acc[gg*6+0]);
                    acc[gg*6+1] = fmaf(a, w0.y, acc[gg*6+1]);
                    acc[gg*6+2] = fmaf(a, w1.x, acc[gg*6+2]);
                    acc[gg*6+3] = fmaf(a, w1.y, acc[gg*6+3]);
                    acc[gg*6+4] = fmaf(a, w2.x, acc[gg*6+4]);
                    acc[gg*6+5] = fmaf(a, w2.y, acc[gg*6+5]);
                }
            }
        }
    }

    __syncthreads();
    {   // write K-partials
        float4* dst = (float4*)&Buf[(ksub*64 + r)*24];
        dst[0] = make_float4(acc[0],  acc[1],  acc[2],  acc[3]);
        dst[1] = make_float4(acc[4],  acc[5],  acc[6],  acc[7]);
        dst[2] = make_float4(acc[8],  acc[9],  acc[10], acc[11]);
        dst[3] = make_float4(acc[12], acc[13], acc[14], acc[15]);
        dst[4] = make_float4(acc[16], acc[17], acc[18], acc[19]);
        dst[5] = make_float4(acc[20], acc[21], acc[22], acc[23]);
    }
    __syncthreads();
    #pragma unroll
    for (int i = 0; i < 6; ++i) {
        int f  = i*256 + tid;            // 0..1535
        int rr = f / 24, j = f % 24;
        float s = Buf[rr*24 + j] + Buf[1536 + rr*24 + j]
                + Buf[3072 + rr*24 + j] + Buf[4608 + rr*24 + j] + Bs[j];
        pre[(rowbase + rr)*24 + j] = s;
    }
}

__global__ __launch_bounds__(64) void qlstm_scan(
    const float* __restrict__ pre,
    const float* __restrict__ Wf, const float* __restrict__ Wi,
    const float* __restrict__ Wu, const float* __restrict__ Wo,
    float* __restrict__ out)
{
    // 4 threads per batch element (one per gate). 16 batches per 64-thread block.
    __shared__ float act_s[2][16][28];   // stride 28: 2-way banks only

    const int lane = threadIdx.x;
    const int bl   = lane >> 2;          // batch-local 0..15
    const int g    = lane & 3;           // 0=f 1=i 2=u 3=o
    const int b    = blockIdx.x * 16 + bl;

    // this gate's recurrent weights in registers (rows 512..517 of Wg)
    const float* Wg = (g==0)?Wf:(g==1)?Wi:(g==2)?Wu:Wo;
    float Wh[6][6];
    #pragma unroll
    for (int j = 0; j < 6; ++j)
        #pragma unroll
        for (int w = 0; w < 6; ++w)
            Wh[j][w] = Wg[(512 + j)*6 + w];

    // tanh(x) = 2*sigmoid(2x)-1 -> branchless per-gate constants
    const float k1 = (g==2) ? 2.f : 1.f;
    const float k2 = (g==2) ? 2.f : 1.f;
    const float k3 = (g==2) ? -1.f : 0.f;

    float h[6], c[6];
    #pragma unroll
    for (int w = 0; w < 6; ++w) { h[w] = 0.f; c[w] = 0.f; }

    // prefetch t=0
    const float* p0 = pre + b*24 + g*6;
    float2 x0 = *(const float2*)(p0);
    float2 x1 = *(const float2*)(p0 + 2);
    float2 x2 = *(const float2*)(p0 + 4);

    for (int t = 0; t < 64; ++t) {
        float xw[6] = {x0.x, x0.y, x1.x, x1.y, x2.x, x2.y};
        // prefetch next step (address independent of state)
        int tn = (t < 63) ? (t + 1) : 63;
        const float* pn = pre + (tn*256 + b)*24 + g*6;
        x0 = *(const float2*)(pn);
        x1 = *(const float2*)(pn + 2);
        x2 = *(const float2*)(pn + 4);

        float a[6];
        #pragma unroll
        for (int w = 0; w < 6; ++w) a[w] = xw[w];
        #pragma unroll
        for (int j = 0; j < 6; ++j)
            #pragma unroll
            for (int w = 0; w < 6; ++w)
                a[w] = fmaf(h[j], Wh[j][w], a[w]);

        float C[6];
        #pragma unroll
        for (int w = 0; w < 6; ++w) C[w] = __cosf(a[w]);

        float z[6];
        z[1] = C[0]*C[1];
        z[2] = z[1]*C[2];
        z[3] = z[2]*C[3];
        z[4] = z[3]*C[4];
        z[5] = z[4]*C[5];
        z[0] = (C[1]*C[2])*((C[3]*C[4])*C[5]);

        float act[6];
        #pragma unroll
        for (int w = 0; w < 6; ++w) {
            float e = __expf(-k1 * z[w]);
            act[w] = fmaf(k2, fast_rcp(1.f + e), k3);
        }

        const int par = t & 1;
        float2* ap = (float2*)&act_s[par][bl][g*6];
        ap[0] = make_float2(act[0], act[1]);
        ap[1] = make_float2(act[2], act[3]);
        ap[2] = make_float2(act[4], act[5]);
        __syncthreads();

        const float4* Aq = (const float4*)&act_s[par][bl][0];
        float4 q0 = Aq[0], q1 = Aq[1], q2 = Aq[2], q3 = Aq[3], q4 = Aq[4], q5 = Aq[5];
        float F[6] = {q0.x, q0.y, q0.z, q0.w, q1.x, q1.y};
        float I[6] = {q1.z, q1.w, q2.x, q2.y, q2.z, q2.w};
        float U[6] = {q3.x, q3.y, q3.z, q3.w, q4.x, q4.y};
        float O[6] = {q4.z, q4.w, q5.x, q5.y, q5.z, q5.w};

        #pragma unroll
        for (int w = 0; w < 6; ++w) {
            c[w] = fmaf(F[w], c[w], I[w]*U[w]);
            float e  = __expf(-2.f * c[w]);
            float tc = fmaf(2.f, fast_rcp(1.f + e), -1.f);
            h[w] = O[w]*tc;
        }

        if (g < 3) {
            float2 v;
            v.x = (g==0) ? h[0] : (g==1) ? h[2] : h[4];
            v.y = (g==0) ? h[1] : (g==1) ? h[3] : h[5];
            *(float2*)(out + (t*256 + b)*6 + g*2) = v;
        }
    }

    if (g < 3) {
        float2 v;
        v.x = (g==0) ? h[0] : (g==1) ? h[2] : h[4];
        v.y = (g==0) ? h[1] : (g==1) ? h[3] : h[5];
        *(float2*)(out + 64*256*6 + b*6 + g*2) = v;
        float2 u;
        u.x = (g==0) ? c[0] : (g==1) ? c[2] : c[4];
        u.y = (g==0) ? c[1] : (g==1) ? c[3] : c[5];
        *(float2*)(out + 64*256*6 + 256*6 + b*6 + g*2) = u;
    }
}

extern "C" void kernel_launch(void* const* d_in, const int* in_sizes, int n_in,
                              void* d_out, int out_size, void* d_ws, size_t ws_size,
                              hipStream_t stream) {
    const float* X   = (const float*)d_in[0];
    const float* Wf  = (const float*)d_in[1];
    const float* bf_ = (const float*)d_in[2];
    const float* Wi  = (const float*)d_in[3];
    const float* bi_ = (const float*)d_in[4];
    const float* Wu  = (const float*)d_in[5];
    const float* bu_ = (const float*)d_in[6];
    const float* Wo  = (const float*)d_in[7];
    const float* bo_ = (const float*)d_in[8];
    const float* thf = (const float*)d_in[9];
    const float* thi = (const float*)d_in[10];
    const float* thu = (const float*)d_in[11];
    const float* tho = (const float*)d_in[12];

    float* pre = (float*)d_ws;           // 16384*24 floats = 1.57 MB
    float* out = (float*)d_out;

    gemm_pre<<<256, 256, 0, stream>>>(X, Wf, bf_, Wi, bi_, Wu, bu_, Wo, bo_,
                                      thf, thi, thu, tho, pre);
    qlstm_scan<<<16, 64, 0, stream>>>(pre, Wf, Wi, Wu, Wo, out);
}